// Round 2
// baseline (679.559 us; speedup 1.0000x reference)
//
#include <hip/hip_runtime.h>

// ---------------------------------------------------------------------------
// SDGL gcn_module: out = W1*x + W2*(G1 x) + W3*(G2 x) + b
//   G1 = AL^2 + AS - AS*AL ; G2 = AL^3 + AS^2 - AS^2*AL   (per-slice linear op)
// Pipeline:
//   1) cast AL,AS -> bf16 (natural + transposed)
//   2) transpose-cast x[b,c,w,t] -> xT[(b,c,t), w] bf16   (B^T operand)
//   3) 5 batched 1024^3 bf16 GEMMs -> G pieces; assemble G[2048,1024] bf16
//   4) main GEMM U[(g,n),(b,c,t)] = G @ xT^T   (M=2048,N=32768,K=1024)
//   5) fp32 channel mix (single pass, all 32 out-channels per thread)
// ---------------------------------------------------------------------------

typedef __bf16 bf16x8 __attribute__((ext_vector_type(8)));
typedef float f32x4 __attribute__((ext_vector_type(4)));
typedef unsigned int u32x4 __attribute__((ext_vector_type(4)));
typedef unsigned int u32x2 __attribute__((ext_vector_type(2)));

__device__ __forceinline__ unsigned short f2bf(float f) {
  unsigned u = __builtin_bit_cast(unsigned, f);
  u += 0x7fffu + ((u >> 16) & 1u);           // round-to-nearest-even
  return (unsigned short)(u >> 16);
}
__device__ __forceinline__ float bf2f(unsigned short h) {
  unsigned u = ((unsigned)h) << 16;
  return __builtin_bit_cast(float, u);
}

// ---------------- workspace layout (bytes) ----------------
static constexpr size_t OFF_XT    = 0;                      // 32768*1024*2 = 64 MiB
static constexpr size_t OFF_U     = 67108864;               // 2048*32768*2 = 128 MiB
static constexpr size_t OFF_ALBF  = 201326592;              // each small mat 2 MiB
static constexpr size_t OFF_ALT   = OFF_ALBF  + 2097152;
static constexpr size_t OFF_ASBF  = OFF_ALT   + 2097152;
static constexpr size_t OFF_AST   = OFF_ASBF  + 2097152;
static constexpr size_t OFF_AL2   = OFF_AST   + 2097152;
static constexpr size_t OFF_AL2T  = OFF_AL2   + 2097152;
static constexpr size_t OFF_ASAL  = OFF_AL2T  + 2097152;
static constexpr size_t OFF_AS2   = OFF_ASAL  + 2097152;
static constexpr size_t OFF_AL3   = OFF_AS2   + 2097152;
static constexpr size_t OFF_AS2AL = OFF_AL3   + 2097152;
static constexpr size_t OFF_G     = OFF_AS2AL + 2097152;    // 2048*1024*2 = 4 MiB
// total = 226,492,416 bytes

// ---------------- simple fp32 -> bf16 cast ----------------
__global__ __launch_bounds__(256) void k_cast_bf16(const float* __restrict__ src,
                                                   unsigned short* __restrict__ dst,
                                                   int n4) {
  int i = blockIdx.x * 256 + threadIdx.x;
  if (i < n4) {
    float4 v = *((const float4*)src + i);
    unsigned lo = (unsigned)f2bf(v.x) | ((unsigned)f2bf(v.y) << 16);
    unsigned hi = (unsigned)f2bf(v.z) | ((unsigned)f2bf(v.w) << 16);
    u32x2 pk = {lo, hi};
    *(u32x2*)(dst + (size_t)i * 4) = pk;
  }
}

// ---------------- 64x64 tiled transpose + cast ----------------
// src: [S][R][Cc] fp32 (slice z) ; dst: [S][Cc][R] bf16. grid (R/64, Cc/64, S)
__global__ __launch_bounds__(256) void k_transpose_cast(const float* __restrict__ src,
                                                        unsigned short* __restrict__ dst,
                                                        int R, int Cc) {
  __shared__ float Xs[64][65];
  const int tid = threadIdx.x;
  const size_t slice = (size_t)blockIdx.z * (size_t)R * (size_t)Cc;
  const float* s = src + slice;
  unsigned short* d = dst + slice;
  const int r0 = blockIdx.x * 64, c0 = blockIdx.y * 64;
  const int lrow = tid >> 4, lc4 = tid & 15;
#pragma unroll
  for (int rr = 0; rr < 4; rr++) {
    int row = rr * 16 + lrow;
    float4 v = *(const float4*)(s + (size_t)(r0 + row) * Cc + c0 + lc4 * 4);
    Xs[row][lc4 * 4 + 0] = v.x;
    Xs[row][lc4 * 4 + 1] = v.y;
    Xs[row][lc4 * 4 + 2] = v.z;
    Xs[row][lc4 * 4 + 3] = v.w;
  }
  __syncthreads();
  const int wc = tid & 7;
#pragma unroll
  for (int u = 0; u < 2; u++) {
    int t = u * 32 + (tid >> 3);
    unsigned v0 = (unsigned)f2bf(Xs[wc * 8 + 0][t]) | ((unsigned)f2bf(Xs[wc * 8 + 1][t]) << 16);
    unsigned v1 = (unsigned)f2bf(Xs[wc * 8 + 2][t]) | ((unsigned)f2bf(Xs[wc * 8 + 3][t]) << 16);
    unsigned v2 = (unsigned)f2bf(Xs[wc * 8 + 4][t]) | ((unsigned)f2bf(Xs[wc * 8 + 5][t]) << 16);
    unsigned v3 = (unsigned)f2bf(Xs[wc * 8 + 6][t]) | ((unsigned)f2bf(Xs[wc * 8 + 7][t]) << 16);
    u32x4 pk = {v0, v1, v2, v3};
    *(u32x4*)(d + (size_t)(c0 + t) * R + r0 + wc * 8) = pk;
  }
}

// ---------------- core 128x128 bf16 GEMM, C = A * Bt^T ----------------
// A:[M,K] bf16 k-contig, Bt:[N,K] bf16 k-contig, C:[M,ldc] bf16. 256 thr, BK=32.
__device__ __forceinline__ void gemm128_bt(const unsigned short* __restrict__ A,
                                           const unsigned short* __restrict__ Bt,
                                           unsigned short* __restrict__ Cp,
                                           int K, size_t ldc, int m0, int n0) {
  __shared__ unsigned short As[128 * 32];
  __shared__ unsigned short Bs[128 * 32];
  const int tid = threadIdx.x;
  const int wave = tid >> 6, lane = tid & 63;
  const int lane15 = lane & 15, quad = lane >> 4;
  const int wm = wave & 1, wn = wave >> 1;
  const int srow = lane >> 2;            // 0..15 staged row within wave's stripe
  const int schunk = (lane & 3) * 8;     // 16B chunk within 64B row

  const unsigned short* gA0 = A + (size_t)(m0 + wave * 16 + srow) * K + schunk;
  const unsigned short* gA1 = A + (size_t)(m0 + 64 + wave * 16 + srow) * K + schunk;
  const unsigned short* gB0 = Bt + (size_t)(n0 + wave * 16 + srow) * K + schunk;
  const unsigned short* gB1 = Bt + (size_t)(n0 + 64 + wave * 16 + srow) * K + schunk;
  unsigned short* lA0 = As + (wave * 16) * 32;
  unsigned short* lA1 = As + (64 + wave * 16) * 32;
  unsigned short* lB0 = Bs + (wave * 16) * 32;
  unsigned short* lB1 = Bs + (64 + wave * 16) * 32;

  f32x4 acc[4][4];
#pragma unroll
  for (int i = 0; i < 4; i++)
#pragma unroll
    for (int j = 0; j < 4; j++) acc[i][j] = (f32x4){0.f, 0.f, 0.f, 0.f};

  const unsigned short* pa = As + (wm * 64 + lane15) * 32 + quad * 8;
  const unsigned short* pb = Bs + (wn * 64 + lane15) * 32 + quad * 8;

  for (int kb = 0; kb < K; kb += 32) {
    __syncthreads();
    __builtin_amdgcn_global_load_lds(
        (const __attribute__((address_space(1))) unsigned int*)(gA0 + kb),
        (__attribute__((address_space(3))) unsigned int*)lA0, 16, 0, 0);
    __builtin_amdgcn_global_load_lds(
        (const __attribute__((address_space(1))) unsigned int*)(gA1 + kb),
        (__attribute__((address_space(3))) unsigned int*)lA1, 16, 0, 0);
    __builtin_amdgcn_global_load_lds(
        (const __attribute__((address_space(1))) unsigned int*)(gB0 + kb),
        (__attribute__((address_space(3))) unsigned int*)lB0, 16, 0, 0);
    __builtin_amdgcn_global_load_lds(
        (const __attribute__((address_space(1))) unsigned int*)(gB1 + kb),
        (__attribute__((address_space(3))) unsigned int*)lB1, 16, 0, 0);
    __syncthreads();

    bf16x8 av[4], bv[4];
#pragma unroll
    for (int mt = 0; mt < 4; mt++) av[mt] = *(const bf16x8*)(pa + mt * 16 * 32);
#pragma unroll
    for (int nt = 0; nt < 4; nt++) bv[nt] = *(const bf16x8*)(pb + nt * 16 * 32);
#pragma unroll
    for (int mt = 0; mt < 4; mt++)
#pragma unroll
      for (int nt = 0; nt < 4; nt++)
        acc[mt][nt] = __builtin_amdgcn_mfma_f32_16x16x32_bf16(av[mt], bv[nt], acc[mt][nt], 0, 0, 0);
  }

#pragma unroll
  for (int mt = 0; mt < 4; mt++) {
#pragma unroll
    for (int nt = 0; nt < 4; nt++) {
      const int col = n0 + wn * 64 + nt * 16 + lane15;
#pragma unroll
      for (int r = 0; r < 4; r++) {
        const int row = m0 + wm * 64 + mt * 16 + quad * 4 + r;
        Cp[(size_t)row * ldc + col] = f2bf(acc[mt][nt][r]);
      }
    }
  }
}

// ---------------- G-precompute GEMMs (batched by z) ----------------
__global__ __launch_bounds__(256) void k_gemm_pre(char* ws, int stage) {
  const unsigned short* A;
  const unsigned short* Bt;
  unsigned short* Cp;
  const int z = blockIdx.z;
  unsigned short* ALbf = (unsigned short*)(ws + OFF_ALBF);
  unsigned short* ALt  = (unsigned short*)(ws + OFF_ALT);
  unsigned short* ASbf = (unsigned short*)(ws + OFF_ASBF);
  unsigned short* ASt  = (unsigned short*)(ws + OFF_AST);
  unsigned short* AL2  = (unsigned short*)(ws + OFF_AL2);
  unsigned short* AL2t = (unsigned short*)(ws + OFF_AL2T);
  unsigned short* ASAL = (unsigned short*)(ws + OFF_ASAL);
  unsigned short* AS2  = (unsigned short*)(ws + OFF_AS2);
  unsigned short* AL3  = (unsigned short*)(ws + OFF_AL3);
  unsigned short* AS2AL= (unsigned short*)(ws + OFF_AS2AL);
  if (stage == 0) {
    if (z == 0)      { A = ALbf; Bt = ALt;  Cp = AL2;  }   // AL^2
    else if (z == 1) { A = ALt;  Bt = ALbf; Cp = AL2t; }   // (AL^2)^T
    else if (z == 2) { A = ASbf; Bt = ALt;  Cp = ASAL; }   // AS*AL
    else             { A = ASbf; Bt = ASt;  Cp = AS2;  }   // AS^2
  } else {
    if (z == 0)      { A = ALbf; Bt = AL2t; Cp = AL3;  }   // AL^3
    else             { A = AS2;  Bt = ALt;  Cp = AS2AL;}   // AS^2*AL
  }
  gemm128_bt(A, Bt, Cp, 1024, 1024, blockIdx.y * 128, blockIdx.x * 128);
}

// ---------------- assemble G = [G1; G2] bf16 ----------------
__global__ __launch_bounds__(256) void k_assemble_G(const unsigned short* __restrict__ AL2,
                                                    const unsigned short* __restrict__ ASAL,
                                                    const float* __restrict__ ASf,
                                                    const unsigned short* __restrict__ AL3,
                                                    const unsigned short* __restrict__ AS2,
                                                    const unsigned short* __restrict__ AS2AL,
                                                    unsigned short* __restrict__ G) {
  int i = blockIdx.x * 256 + threadIdx.x;           // over 1024*1024
  float g1 = bf2f(AL2[i]) + ASf[i] - bf2f(ASAL[i]);
  G[i] = f2bf(g1);
  float g2 = bf2f(AL3[i]) + bf2f(AS2[i]) - bf2f(AS2AL[i]);
  G[1048576 + i] = f2bf(g2);
}

// ---------------- main GEMM: U = G @ xT^T ----------------
__global__ __launch_bounds__(256) void k_gemm_main(const unsigned short* __restrict__ G,
                                                   const unsigned short* __restrict__ xT,
                                                   unsigned short* __restrict__ U) {
  gemm128_bt(G, xT, U, 1024, 32768, blockIdx.y * 128, blockIdx.x * 128);
}

// ---------------- final fp32 channel mix (single pass) ----------------
// out[b,o,n,t] = sum_c W[o,c]*x[b,c,n,t] + W[o,32+c]*U0[n,(b,c,t)]
//                       + W[o,64+c]*U1[n,(b,c,t)] + bias[o]
// Thread owns (n, t-pair), holds all 32 output channels: float2 acc[32].
// Block = 256 thr = 8 n x 32 t-pairs. Grid (128, 16) = 2048 blocks.
// x/U/out read+written exactly once; W loads are wave-uniform -> s_load.
__global__ __launch_bounds__(256) void k_mix(const float* __restrict__ x,
                                             const unsigned short* __restrict__ U,
                                             const float* __restrict__ W,
                                             const float* __restrict__ bm,
                                             float* __restrict__ out) {
  const int tid = threadIdx.x;
  const int b = blockIdx.y;
  const int n = blockIdx.x * 8 + (tid >> 5);
  const int t0 = (tid & 31) * 2;

  const float* xb = x + (size_t)b * 2097152 + (size_t)n * 64 + t0;            // + c*65536
  const unsigned short* U0 = U + (size_t)n * 32768 + b * 2048 + t0;           // + c*64
  const unsigned short* U1 = U + (size_t)(n + 1024) * 32768 + b * 2048 + t0;  // + c*64
  float* ob = out + (size_t)b * 2097152 + (size_t)n * 64 + t0;                // + o*65536

  float2 acc[32];
#pragma unroll
  for (int o = 0; o < 32; o++) acc[o] = make_float2(0.f, 0.f);

#pragma unroll 4
  for (int c = 0; c < 32; c++) {
    const float2 xv = *(const float2*)(xb + (size_t)c * 65536);
    const unsigned ua = *(const unsigned*)(U0 + c * 64);
    const unsigned ub = *(const unsigned*)(U1 + c * 64);
    const float u0a = bf2f((unsigned short)(ua & 0xffffu));
    const float u0b = bf2f((unsigned short)(ua >> 16));
    const float u1a = bf2f((unsigned short)(ub & 0xffffu));
    const float u1b = bf2f((unsigned short)(ub >> 16));
#pragma unroll
    for (int o = 0; o < 32; o++) {
      const float w1 = W[o * 96 + c];
      const float w2 = W[o * 96 + 32 + c];
      const float w3 = W[o * 96 + 64 + c];
      acc[o].x += w1 * xv.x + w2 * u0a + w3 * u1a;
      acc[o].y += w1 * xv.y + w2 * u0b + w3 * u1b;
    }
  }

#pragma unroll
  for (int o = 0; o < 32; o++) {
    const float bo = bm[o];
    float2 s = make_float2(acc[o].x + bo, acc[o].y + bo);
    *(float2*)(ob + (size_t)o * 65536) = s;
  }
}

extern "C" void kernel_launch(void* const* d_in, const int* in_sizes, int n_in,
                              void* d_out, int out_size, void* d_ws, size_t ws_size,
                              hipStream_t stream) {
  const float* x  = (const float*)d_in[0];
  const float* AL = (const float*)d_in[1];
  const float* AS = (const float*)d_in[2];
  const float* W  = (const float*)d_in[3];
  const float* bm = (const float*)d_in[4];
  float* out = (float*)d_out;
  char* ws = (char*)d_ws;

  unsigned short* xT    = (unsigned short*)(ws + OFF_XT);
  unsigned short* U     = (unsigned short*)(ws + OFF_U);
  unsigned short* ALbf  = (unsigned short*)(ws + OFF_ALBF);
  unsigned short* ALt   = (unsigned short*)(ws + OFF_ALT);
  unsigned short* ASbf  = (unsigned short*)(ws + OFF_ASBF);
  unsigned short* ASt   = (unsigned short*)(ws + OFF_AST);
  unsigned short* AL2   = (unsigned short*)(ws + OFF_AL2);
  unsigned short* ASAL  = (unsigned short*)(ws + OFF_ASAL);
  unsigned short* AS2   = (unsigned short*)(ws + OFF_AS2);
  unsigned short* AL3   = (unsigned short*)(ws + OFF_AL3);
  unsigned short* AS2AL = (unsigned short*)(ws + OFF_AS2AL);
  unsigned short* Gm    = (unsigned short*)(ws + OFF_G);

  // 1) small casts + transposes (bf16 operands for precompute GEMMs)
  k_cast_bf16<<<1024, 256, 0, stream>>>(AL, ALbf, 262144);
  k_cast_bf16<<<1024, 256, 0, stream>>>(AS, ASbf, 262144);
  k_transpose_cast<<<dim3(16, 16, 1), 256, 0, stream>>>(AL, ALt, 1024, 1024);
  k_transpose_cast<<<dim3(16, 16, 1), 256, 0, stream>>>(AS, ASt, 1024, 1024);
  // 2) x[b,c,w,t] -> xT[(b,c,t), w]  (512 slices of 1024x64)
  k_transpose_cast<<<dim3(16, 1, 512), 256, 0, stream>>>(x, xT, 1024, 64);
  // 3) G pieces: {AL2, AL2t, ASAL, AS2} then {AL3, AS2AL}
  k_gemm_pre<<<dim3(8, 8, 4), 256, 0, stream>>>(ws, 0);
  k_gemm_pre<<<dim3(8, 8, 2), 256, 0, stream>>>(ws, 1);
  k_assemble_G<<<4096, 256, 0, stream>>>(AL2, ASAL, AS, AL3, AS2, AS2AL, Gm);
  // 4) U[(g,n), (b,c,t)] = G @ xT^T   M=2048 N=32768 K=1024
  k_gemm_main<<<dim3(256, 16, 1), 256, 0, stream>>>(Gm, xT, U);
  // 5) fused fp32 channel mix + bias (single pass)
  k_mix<<<dim3(128, 16, 1), 256, 0, stream>>>(x, U, W, bm, out);
}

// Round 3
// 519.681 us; speedup vs baseline: 1.3076x; 1.3076x over previous
//
#include <hip/hip_runtime.h>

// ---------------------------------------------------------------------------
// SDGL gcn_module: out = W1*x + W2*(G1 x) + W3*(G2 x) + b
//   G1 = AL^2 + AS - AS*AL ; G2 = AL^3 + AS^2 - AS2*AL   (per-slice linear op)
// Pipeline:
//   1) cast AL,AS -> bf16 (natural + transposed)
//   2) transpose-cast x[b,c,w,t] -> xT[(b,c,t), w] bf16   (B^T operand)
//   3) 5 batched 1024^3 bf16 GEMMs -> G pieces; assemble G[2048,1024] bf16
//   4) main GEMM U[(g,n),(b,c,t)] = G @ xT^T   (M=2048,N=32768,K=1024)
//   5) MFMA epilogue: out[j=(b,n,t), o] = H[j,0:96]·W~[o,:]^T + bias,
//      H = [x | U0 | U1] staged per-block into swizzled LDS (R2's VALU mix
//      spilled its 64-reg accumulator; K=96 mix belongs on matrix cores).
// ---------------------------------------------------------------------------

typedef __bf16 bf16x8 __attribute__((ext_vector_type(8)));
typedef float f32x4 __attribute__((ext_vector_type(4)));
typedef unsigned int u32x4 __attribute__((ext_vector_type(4)));
typedef unsigned int u32x2 __attribute__((ext_vector_type(2)));

__device__ __forceinline__ unsigned short f2bf(float f) {
  unsigned u = __builtin_bit_cast(unsigned, f);
  u += 0x7fffu + ((u >> 16) & 1u);           // round-to-nearest-even
  return (unsigned short)(u >> 16);
}
__device__ __forceinline__ float bf2f(unsigned short h) {
  unsigned u = ((unsigned)h) << 16;
  return __builtin_bit_cast(float, u);
}

// ---------------- workspace layout (bytes) ----------------
static constexpr size_t OFF_XT    = 0;                      // 32768*1024*2 = 64 MiB
static constexpr size_t OFF_U     = 67108864;               // 2048*32768*2 = 128 MiB
static constexpr size_t OFF_ALBF  = 201326592;              // each small mat 2 MiB
static constexpr size_t OFF_ALT   = OFF_ALBF  + 2097152;
static constexpr size_t OFF_ASBF  = OFF_ALT   + 2097152;
static constexpr size_t OFF_AST   = OFF_ASBF  + 2097152;
static constexpr size_t OFF_AL2   = OFF_AST   + 2097152;
static constexpr size_t OFF_AL2T  = OFF_AL2   + 2097152;
static constexpr size_t OFF_ASAL  = OFF_AL2T  + 2097152;
static constexpr size_t OFF_AS2   = OFF_ASAL  + 2097152;
static constexpr size_t OFF_AL3   = OFF_AS2   + 2097152;
static constexpr size_t OFF_AS2AL = OFF_AL3   + 2097152;
static constexpr size_t OFF_G     = OFF_AS2AL + 2097152;    // 2048*1024*2 = 4 MiB
// Wbf (32x96 bf16, 6 KiB) reuses OFF_ALBF after the pre-GEMMs retire ALbf.
// total = 226,492,416 bytes

// ---------------- simple fp32 -> bf16 cast ----------------
__global__ __launch_bounds__(256) void k_cast_bf16(const float* __restrict__ src,
                                                   unsigned short* __restrict__ dst,
                                                   int n4) {
  int i = blockIdx.x * 256 + threadIdx.x;
  if (i < n4) {
    float4 v = *((const float4*)src + i);
    unsigned lo = (unsigned)f2bf(v.x) | ((unsigned)f2bf(v.y) << 16);
    unsigned hi = (unsigned)f2bf(v.z) | ((unsigned)f2bf(v.w) << 16);
    u32x2 pk = {lo, hi};
    *(u32x2*)(dst + (size_t)i * 4) = pk;
  }
}

// ---------------- 64x64 tiled transpose + cast ----------------
// src: [S][R][Cc] fp32 (slice z) ; dst: [S][Cc][R] bf16. grid (R/64, Cc/64, S)
__global__ __launch_bounds__(256) void k_transpose_cast(const float* __restrict__ src,
                                                        unsigned short* __restrict__ dst,
                                                        int R, int Cc) {
  __shared__ float Xs[64][65];
  const int tid = threadIdx.x;
  const size_t slice = (size_t)blockIdx.z * (size_t)R * (size_t)Cc;
  const float* s = src + slice;
  unsigned short* d = dst + slice;
  const int r0 = blockIdx.x * 64, c0 = blockIdx.y * 64;
  const int lrow = tid >> 4, lc4 = tid & 15;
#pragma unroll
  for (int rr = 0; rr < 4; rr++) {
    int row = rr * 16 + lrow;
    float4 v = *(const float4*)(s + (size_t)(r0 + row) * Cc + c0 + lc4 * 4);
    Xs[row][lc4 * 4 + 0] = v.x;
    Xs[row][lc4 * 4 + 1] = v.y;
    Xs[row][lc4 * 4 + 2] = v.z;
    Xs[row][lc4 * 4 + 3] = v.w;
  }
  __syncthreads();
  const int wc = tid & 7;
#pragma unroll
  for (int u = 0; u < 2; u++) {
    int t = u * 32 + (tid >> 3);
    unsigned v0 = (unsigned)f2bf(Xs[wc * 8 + 0][t]) | ((unsigned)f2bf(Xs[wc * 8 + 1][t]) << 16);
    unsigned v1 = (unsigned)f2bf(Xs[wc * 8 + 2][t]) | ((unsigned)f2bf(Xs[wc * 8 + 3][t]) << 16);
    unsigned v2 = (unsigned)f2bf(Xs[wc * 8 + 4][t]) | ((unsigned)f2bf(Xs[wc * 8 + 5][t]) << 16);
    unsigned v3 = (unsigned)f2bf(Xs[wc * 8 + 6][t]) | ((unsigned)f2bf(Xs[wc * 8 + 7][t]) << 16);
    u32x4 pk = {v0, v1, v2, v3};
    *(u32x4*)(d + (size_t)(c0 + t) * R + r0 + wc * 8) = pk;
  }
}

// ---------------- core 128x128 bf16 GEMM, C = A * Bt^T ----------------
// A:[M,K] bf16 k-contig, Bt:[N,K] bf16 k-contig, C:[M,ldc] bf16. 256 thr, BK=32.
__device__ __forceinline__ void gemm128_bt(const unsigned short* __restrict__ A,
                                           const unsigned short* __restrict__ Bt,
                                           unsigned short* __restrict__ Cp,
                                           int K, size_t ldc, int m0, int n0) {
  __shared__ unsigned short As[128 * 32];
  __shared__ unsigned short Bs[128 * 32];
  const int tid = threadIdx.x;
  const int wave = tid >> 6, lane = tid & 63;
  const int lane15 = lane & 15, quad = lane >> 4;
  const int wm = wave & 1, wn = wave >> 1;
  const int srow = lane >> 2;            // 0..15 staged row within wave's stripe
  const int schunk = (lane & 3) * 8;     // 16B chunk within 64B row

  const unsigned short* gA0 = A + (size_t)(m0 + wave * 16 + srow) * K + schunk;
  const unsigned short* gA1 = A + (size_t)(m0 + 64 + wave * 16 + srow) * K + schunk;
  const unsigned short* gB0 = Bt + (size_t)(n0 + wave * 16 + srow) * K + schunk;
  const unsigned short* gB1 = Bt + (size_t)(n0 + 64 + wave * 16 + srow) * K + schunk;
  unsigned short* lA0 = As + (wave * 16) * 32;
  unsigned short* lA1 = As + (64 + wave * 16) * 32;
  unsigned short* lB0 = Bs + (wave * 16) * 32;
  unsigned short* lB1 = Bs + (64 + wave * 16) * 32;

  f32x4 acc[4][4];
#pragma unroll
  for (int i = 0; i < 4; i++)
#pragma unroll
    for (int j = 0; j < 4; j++) acc[i][j] = (f32x4){0.f, 0.f, 0.f, 0.f};

  const unsigned short* pa = As + (wm * 64 + lane15) * 32 + quad * 8;
  const unsigned short* pb = Bs + (wn * 64 + lane15) * 32 + quad * 8;

  for (int kb = 0; kb < K; kb += 32) {
    __syncthreads();
    __builtin_amdgcn_global_load_lds(
        (const __attribute__((address_space(1))) unsigned int*)(gA0 + kb),
        (__attribute__((address_space(3))) unsigned int*)lA0, 16, 0, 0);
    __builtin_amdgcn_global_load_lds(
        (const __attribute__((address_space(1))) unsigned int*)(gA1 + kb),
        (__attribute__((address_space(3))) unsigned int*)lA1, 16, 0, 0);
    __builtin_amdgcn_global_load_lds(
        (const __attribute__((address_space(1))) unsigned int*)(gB0 + kb),
        (__attribute__((address_space(3))) unsigned int*)lB0, 16, 0, 0);
    __builtin_amdgcn_global_load_lds(
        (const __attribute__((address_space(1))) unsigned int*)(gB1 + kb),
        (__attribute__((address_space(3))) unsigned int*)lB1, 16, 0, 0);
    __syncthreads();

    bf16x8 av[4], bv[4];
#pragma unroll
    for (int mt = 0; mt < 4; mt++) av[mt] = *(const bf16x8*)(pa + mt * 16 * 32);
#pragma unroll
    for (int nt = 0; nt < 4; nt++) bv[nt] = *(const bf16x8*)(pb + nt * 16 * 32);
#pragma unroll
    for (int mt = 0; mt < 4; mt++)
#pragma unroll
      for (int nt = 0; nt < 4; nt++)
        acc[mt][nt] = __builtin_amdgcn_mfma_f32_16x16x32_bf16(av[mt], bv[nt], acc[mt][nt], 0, 0, 0);
  }

#pragma unroll
  for (int mt = 0; mt < 4; mt++) {
#pragma unroll
    for (int nt = 0; nt < 4; nt++) {
      const int col = n0 + wn * 64 + nt * 16 + lane15;
#pragma unroll
      for (int r = 0; r < 4; r++) {
        const int row = m0 + wm * 64 + mt * 16 + quad * 4 + r;
        Cp[(size_t)row * ldc + col] = f2bf(acc[mt][nt][r]);
      }
    }
  }
}

// ---------------- G-precompute GEMMs (batched by z) ----------------
__global__ __launch_bounds__(256) void k_gemm_pre(char* ws, int stage) {
  const unsigned short* A;
  const unsigned short* Bt;
  unsigned short* Cp;
  const int z = blockIdx.z;
  unsigned short* ALbf = (unsigned short*)(ws + OFF_ALBF);
  unsigned short* ALt  = (unsigned short*)(ws + OFF_ALT);
  unsigned short* ASbf = (unsigned short*)(ws + OFF_ASBF);
  unsigned short* ASt  = (unsigned short*)(ws + OFF_AST);
  unsigned short* AL2  = (unsigned short*)(ws + OFF_AL2);
  unsigned short* AL2t = (unsigned short*)(ws + OFF_AL2T);
  unsigned short* ASAL = (unsigned short*)(ws + OFF_ASAL);
  unsigned short* AS2  = (unsigned short*)(ws + OFF_AS2);
  unsigned short* AL3  = (unsigned short*)(ws + OFF_AL3);
  unsigned short* AS2AL= (unsigned short*)(ws + OFF_AS2AL);
  if (stage == 0) {
    if (z == 0)      { A = ALbf; Bt = ALt;  Cp = AL2;  }   // AL^2
    else if (z == 1) { A = ALt;  Bt = ALbf; Cp = AL2t; }   // (AL^2)^T
    else if (z == 2) { A = ASbf; Bt = ALt;  Cp = ASAL; }   // AS*AL
    else             { A = ASbf; Bt = ASt;  Cp = AS2;  }   // AS^2
  } else {
    if (z == 0)      { A = ALbf; Bt = AL2t; Cp = AL3;  }   // AL^3
    else             { A = AS2;  Bt = ALt;  Cp = AS2AL;}   // AS^2*AL
  }
  gemm128_bt(A, Bt, Cp, 1024, 1024, blockIdx.y * 128, blockIdx.x * 128);
}

// ---------------- assemble G = [G1; G2] bf16 ----------------
__global__ __launch_bounds__(256) void k_assemble_G(const unsigned short* __restrict__ AL2,
                                                    const unsigned short* __restrict__ ASAL,
                                                    const float* __restrict__ ASf,
                                                    const unsigned short* __restrict__ AL3,
                                                    const unsigned short* __restrict__ AS2,
                                                    const unsigned short* __restrict__ AS2AL,
                                                    unsigned short* __restrict__ G) {
  int i = blockIdx.x * 256 + threadIdx.x;           // over 1024*1024
  float g1 = bf2f(AL2[i]) + ASf[i] - bf2f(ASAL[i]);
  G[i] = f2bf(g1);
  float g2 = bf2f(AL3[i]) + bf2f(AS2[i]) - bf2f(AS2AL[i]);
  G[1048576 + i] = f2bf(g2);
}

// ---------------- main GEMM: U = G @ xT^T ----------------
__global__ __launch_bounds__(256) void k_gemm_main(const unsigned short* __restrict__ G,
                                                   const unsigned short* __restrict__ xT,
                                                   unsigned short* __restrict__ U) {
  gemm128_bt(G, xT, U, 1024, 32768, blockIdx.y * 128, blockIdx.x * 128);
}

// ---------------- MFMA epilogue ----------------
// out[b,o,n,t] = sum_k W~[o,k] * H[k, (b,n,t)] + bias[o]
//   H rows: k<32 -> x[b,c,n,t]; k in [32,64) -> U0; [64,96) -> U1.
// Block = (b, n-pair): j-tile = 128 (2 n x 64 t). LDS Hs[128][128] bf16
// (K padded 96->128 for alignment); chunk-of-8 XOR swizzle keeps ds_read_b128
// 16B-aligned while spreading banks (stride 128 shorts alone aliases all rows
// to one bank class). 32 KB LDS -> 5 blocks/CU.
__device__ __forceinline__ int swz_off(int j, int kc) {
  int s = (j ^ (j >> 3) ^ (j >> 6)) & 7;
  return (kc ^ s) << 3;
}

__global__ __launch_bounds__(256) void k_mix_mfma(const float* __restrict__ x,
                                                  const unsigned short* __restrict__ U,
                                                  const unsigned short* __restrict__ Wbf,
                                                  const float* __restrict__ bm,
                                                  float* __restrict__ out) {
  __shared__ unsigned short Hs[128 * 128];
  const int tid = threadIdx.x;
  const int b  = blockIdx.x >> 9;
  const int n0 = (blockIdx.x & 511) * 2;

  // ---- stage x (coalesced fp32 rows -> bf16, k=c columns of Hs) ----
  const float* xb = x + (size_t)b * 2097152 + (size_t)n0 * 64;
#pragma unroll
  for (int i = 0; i < 4; i++) {
    int q = tid + 256 * i;          // 1024 float4 chunks
    int p = q >> 4;                 // 0..63 = c*2+nn
    int c = p >> 1, nn = p & 1;
    int t0 = (q & 15) * 4;
    float4 v = *(const float4*)(xb + (size_t)c * 65536 + nn * 64 + t0);
    int kc = c >> 3, wi = c & 7;
    float vv[4] = {v.x, v.y, v.z, v.w};
#pragma unroll
    for (int e = 0; e < 4; e++) {
      int j = nn * 64 + t0 + e;
      Hs[j * 128 + swz_off(j, kc) + wi] = f2bf(vv[e]);
    }
  }
  // ---- stage U (rows are (c*64+t)-contiguous -> dwordx4, k=32+g*32+c) ----
#pragma unroll
  for (int i = 0; i < 4; i++) {
    int q = tid + 256 * i;          // 1024 8-short chunks
    int row = q >> 8;               // 0..3 = g*2+nn
    int g = row >> 1, nn = row & 1;
    int s8 = (q & 255) * 8;
    int c = s8 >> 6, t0 = s8 & 63;
    const unsigned short* src =
        U + (size_t)(g * 1024 + n0 + nn) * 32768 + (size_t)b * 2048 + s8;
    u32x4 v = *(const u32x4*)src;
    int kc = 4 + g * 4 + (c >> 3), wi = c & 7;
#pragma unroll
    for (int e = 0; e < 4; e++) {
      int j0 = nn * 64 + t0 + 2 * e;
      unsigned w = v[e];
      Hs[j0 * 128 + swz_off(j0, kc) + wi]       = (unsigned short)(w & 0xffffu);
      Hs[(j0 + 1) * 128 + swz_off(j0 + 1, kc) + wi] = (unsigned short)(w >> 16);
    }
  }
  __syncthreads();

  // ---- K=96 MFMA: per wave 2 j-tiles x 2 o-tiles ----
  const int wave = tid >> 6, lane = tid & 63;
  const int lane15 = lane & 15, quad = lane >> 4;
  f32x4 acc[2][2];
#pragma unroll
  for (int jt = 0; jt < 2; jt++)
#pragma unroll
    for (int ot = 0; ot < 2; ot++) acc[jt][ot] = (f32x4){0.f, 0.f, 0.f, 0.f};

#pragma unroll
  for (int kchunk = 0; kchunk < 3; kchunk++) {
    bf16x8 bv[2];
#pragma unroll
    for (int ot = 0; ot < 2; ot++)
      bv[ot] = *(const bf16x8*)(Wbf + (ot * 16 + lane15) * 96 + kchunk * 32 + quad * 8);
#pragma unroll
    for (int jt = 0; jt < 2; jt++) {
      int j = wave * 32 + jt * 16 + lane15;
      bf16x8 av = *(const bf16x8*)(Hs + j * 128 + swz_off(j, kchunk * 4 + quad));
#pragma unroll
      for (int ot = 0; ot < 2; ot++)
        acc[jt][ot] = __builtin_amdgcn_mfma_f32_16x16x32_bf16(av, bv[ot], acc[jt][ot], 0, 0, 0);
    }
  }

  // ---- store + bias: C frag col=lane&15 (o), row=quad*4+r (j) ----
#pragma unroll
  for (int jt = 0; jt < 2; jt++) {
#pragma unroll
    for (int ot = 0; ot < 2; ot++) {
      int col = ot * 16 + lane15;
      float bo = bm[col];
#pragma unroll
      for (int r = 0; r < 4; r++) {
        int j = wave * 32 + jt * 16 + quad * 4 + r;
        int nn = j >> 6, t = j & 63;
        out[(size_t)b * 2097152 + (size_t)col * 65536 + (size_t)(n0 + nn) * 64 + t] =
            acc[jt][ot][r] + bo;
      }
    }
  }
}

extern "C" void kernel_launch(void* const* d_in, const int* in_sizes, int n_in,
                              void* d_out, int out_size, void* d_ws, size_t ws_size,
                              hipStream_t stream) {
  const float* x  = (const float*)d_in[0];
  const float* AL = (const float*)d_in[1];
  const float* AS = (const float*)d_in[2];
  const float* W  = (const float*)d_in[3];
  const float* bm = (const float*)d_in[4];
  float* out = (float*)d_out;
  char* ws = (char*)d_ws;

  unsigned short* xT    = (unsigned short*)(ws + OFF_XT);
  unsigned short* U     = (unsigned short*)(ws + OFF_U);
  unsigned short* ALbf  = (unsigned short*)(ws + OFF_ALBF);
  unsigned short* ALt   = (unsigned short*)(ws + OFF_ALT);
  unsigned short* ASbf  = (unsigned short*)(ws + OFF_ASBF);
  unsigned short* ASt   = (unsigned short*)(ws + OFF_AST);
  unsigned short* AL2   = (unsigned short*)(ws + OFF_AL2);
  unsigned short* ASAL  = (unsigned short*)(ws + OFF_ASAL);
  unsigned short* AS2   = (unsigned short*)(ws + OFF_AS2);
  unsigned short* AL3   = (unsigned short*)(ws + OFF_AL3);
  unsigned short* AS2AL = (unsigned short*)(ws + OFF_AS2AL);
  unsigned short* Gm    = (unsigned short*)(ws + OFF_G);
  unsigned short* Wbf   = (unsigned short*)(ws + OFF_ALBF);  // reused after pre-GEMMs

  // 1) small casts + transposes (bf16 operands for precompute GEMMs)
  k_cast_bf16<<<1024, 256, 0, stream>>>(AL, ALbf, 262144);
  k_cast_bf16<<<1024, 256, 0, stream>>>(AS, ASbf, 262144);
  k_transpose_cast<<<dim3(16, 16, 1), 256, 0, stream>>>(AL, ALt, 1024, 1024);
  k_transpose_cast<<<dim3(16, 16, 1), 256, 0, stream>>>(AS, ASt, 1024, 1024);
  // 2) x[b,c,w,t] -> xT[(b,c,t), w]  (512 slices of 1024x64)
  k_transpose_cast<<<dim3(16, 1, 512), 256, 0, stream>>>(x, xT, 1024, 64);
  // 3) G pieces: {AL2, AL2t, ASAL, AS2} then {AL3, AS2AL}
  k_gemm_pre<<<dim3(8, 8, 4), 256, 0, stream>>>(ws, 0);
  k_gemm_pre<<<dim3(8, 8, 2), 256, 0, stream>>>(ws, 1);
  k_assemble_G<<<4096, 256, 0, stream>>>(AL2, ASAL, AS, AL3, AS2, AS2AL, Gm);
  // 3b) W -> bf16 (3072 floats = 768 float4), into retired ALbf slot
  k_cast_bf16<<<3, 256, 0, stream>>>(W, Wbf, 768);
  // 4) U[(g,n), (b,c,t)] = G @ xT^T   M=2048 N=32768 K=1024
  k_gemm_main<<<dim3(256, 16, 1), 256, 0, stream>>>(Gm, xT, U);
  // 5) MFMA epilogue: out = H @ W~^T + bias  (8192 blocks of 128j x 32o)
  k_mix_mfma<<<dim3(8192, 1, 1), 256, 0, stream>>>(x, U, Wbf, bm, out);
}